// Round 1
// baseline (284.982 us; speedup 1.0000x reference)
//
#include <hip/hip_runtime.h>
#include <math.h>

#define NN 100000
#define DEG 16
#define F_IN 128
#define F_OUT 32
#define NH 4
#define FTOT 128  // NH * F_OUT

// ---------------------------------------------------------------------------
// Kernel 1: t[n][f] = sum_i x[n][i] * W[f][i]   (f = h*32+o, W = Ws flattened)
//           s_src[n][h] = sum_o t[n][h*32+o] * As[h*64+o]
//           s_dst[n][h] = sum_o t[n][h*32+o] * As[h*64+32+o]
// Tile: 64 nodes x 64 features per block (blockIdx.y = feature half / head pair).
// LDS: Wt[i][f] (transposed W half, pad 68) + xT[i][j] (transposed x tile).
// Per lane: 4 nodes x 4 features register tile; k-loop = 2x ds_read_b128 + 16 FMA.
// ---------------------------------------------------------------------------
__global__ __launch_bounds__(256) void k1_proj(
    const float* __restrict__ x,    // [NN][128]
    const float* __restrict__ W,    // [128][128]
    const float* __restrict__ As,   // [4][64]
    float* __restrict__ t,          // [NN][128]
    float* __restrict__ ssrc,       // [NN][4]
    float* __restrict__ sdst) {     // [NN][4]
    __shared__ float Wt[128 * 68];  // Wt[i*68 + f], f in [0,64)
    __shared__ float xT[128 * 68];  // xT[i*68 + j], j in [0,64)

    const int tid = threadIdx.x;
    const int base = blockIdx.x * 64;
    const int ftile = blockIdx.y;   // 0 or 1 (heads {0,1} or {2,3})
    const int fbase = ftile * 64;

    // --- stage W transposed: per-lane 128B contiguous global stream,
    //     LDS writes land 2-way per bank (free) ---
    {
        const int f = tid & 63;
        const int i0 = (tid >> 6) * 32;
        const float* src = W + (fbase + f) * F_IN + i0;
#pragma unroll
        for (int k = 0; k < 8; ++k) {
            float4 v = *(const float4*)(src + 4 * k);
            const int i = i0 + 4 * k;
            Wt[(i + 0) * 68 + f] = v.x;
            Wt[(i + 1) * 68 + f] = v.y;
            Wt[(i + 2) * 68 + f] = v.z;
            Wt[(i + 3) * 68 + f] = v.w;
        }
    }
    // --- stage x tile transposed ---
    {
        const int j = tid & 63;
        const int i0 = (tid >> 6) * 32;
        int n = base + j;
        if (n >= NN) n = NN - 1;  // clamp; stores are guarded below
        const float* src = x + (long)n * F_IN + i0;
#pragma unroll
        for (int k = 0; k < 8; ++k) {
            float4 v = *(const float4*)(src + 4 * k);
            const int i = i0 + 4 * k;
            xT[(i + 0) * 68 + j] = v.x;
            xT[(i + 1) * 68 + j] = v.y;
            xT[(i + 2) * 68 + j] = v.z;
            xT[(i + 3) * 68 + j] = v.w;
        }
    }
    __syncthreads();

    const int lane = tid & 63;
    const int wv = tid >> 6;
    const int l = lane & 15;          // feature quad index: features 4l..4l+3
    const int gg = lane >> 4;         // node subgroup in wave
    const int nloc = wv * 16 + gg * 4;  // block-local node base (4 nodes/lane)

    float acc[4][4];
#pragma unroll
    for (int j = 0; j < 4; ++j)
#pragma unroll
        for (int q = 0; q < 4; ++q) acc[j][q] = 0.f;

#pragma unroll 8
    for (int i = 0; i < 128; ++i) {
        const float4 w4 = *(const float4*)&Wt[i * 68 + 4 * l];
        const float4 xv = *(const float4*)&xT[i * 68 + nloc];
        acc[0][0] += xv.x * w4.x; acc[0][1] += xv.x * w4.y;
        acc[0][2] += xv.x * w4.z; acc[0][3] += xv.x * w4.w;
        acc[1][0] += xv.y * w4.x; acc[1][1] += xv.y * w4.y;
        acc[1][2] += xv.y * w4.z; acc[1][3] += xv.y * w4.w;
        acc[2][0] += xv.z * w4.x; acc[2][1] += xv.z * w4.y;
        acc[2][2] += xv.z * w4.z; acc[2][3] += xv.z * w4.w;
        acc[3][0] += xv.w * w4.x; acc[3][1] += xv.w * w4.y;
        acc[3][2] += xv.w * w4.z; acc[3][3] += xv.w * w4.w;
    }

    // --- store t (float4, coalesced across feature quads) ---
#pragma unroll
    for (int j = 0; j < 4; ++j) {
        const int n = base + nloc + j;
        if (n < NN) {
            float4 v = make_float4(acc[j][0], acc[j][1], acc[j][2], acc[j][3]);
            *(float4*)(t + (long)n * FTOT + fbase + 4 * l) = v;
        }
    }

    // --- s_src / s_dst: dot 32 features of one head, reduce over 8 lanes ---
    const int hloc = l >> 3;               // 0/1 within this feature half
    const int hglob = ftile * 2 + hloc;    // global head
    const int o = (l & 7) * 4;             // feature offset within head
    const float4 asv = *(const float4*)(As + hglob * 64 + o);
    const float4 adv = *(const float4*)(As + hglob * 64 + 32 + o);
    float ps[4], pd[4];
#pragma unroll
    for (int j = 0; j < 4; ++j) {
        ps[j] = acc[j][0] * asv.x + acc[j][1] * asv.y +
                acc[j][2] * asv.z + acc[j][3] * asv.w;
        pd[j] = acc[j][0] * adv.x + acc[j][1] * adv.y +
                acc[j][2] * adv.z + acc[j][3] * adv.w;
    }
#pragma unroll
    for (int mask = 1; mask <= 4; mask <<= 1) {
#pragma unroll
        for (int j = 0; j < 4; ++j) {
            ps[j] += __shfl_xor(ps[j], mask);
            pd[j] += __shfl_xor(pd[j], mask);
        }
    }
    if ((l & 7) == 0) {
#pragma unroll
        for (int j = 0; j < 4; ++j) {
            const int n = base + nloc + j;
            if (n < NN) {
                ssrc[(long)n * NH + hglob] = ps[j];
                sdst[(long)n * NH + hglob] = pd[j];
            }
        }
    }
}

// ---------------------------------------------------------------------------
// Kernel 2: one wave per node.
//   scores[h,d] = s_src[n,h] + s_dst[idx_d,h];  e = exp(leaky_relu(scores,0.2))
//   alpha = softmax_d(e)   (softmax OF e — double exponential, as in reference)
//   out[n, f] = elu( sum_d alpha[d, f/32] * t[idx_d][f] )
// Lanes 0..16 own the 17 edges for scoring; all 64 lanes do the feature gather
// (lane owns features f=lane and f=lane+64).
// ---------------------------------------------------------------------------
__global__ __launch_bounds__(256) void k2_attn(
    const int* __restrict__ nidx,   // [NN][16]
    const float* __restrict__ t,    // [NN][128]
    const float* __restrict__ ssrc, // [NN][4]
    const float* __restrict__ sdst, // [NN][4]
    float* __restrict__ out) {      // [NN][128]
    __shared__ float salpha[4][17][4];  // [wave][d][h]
    __shared__ int sidx[4][17];

    const int lane = threadIdx.x & 63;
    const int wv = threadIdx.x >> 6;
    const int n = blockIdx.x * 4 + wv;
    if (n >= NN) return;  // N=100000 divisible by 4, uniform in practice

    // --- phase 1: scores on lanes 0..16 ---
    int myidx = 0;
    float4 sd = make_float4(0.f, 0.f, 0.f, 0.f);
    if (lane < 17) {
        myidx = (lane == 0) ? n : nidx[(long)n * DEG + (lane - 1)];
        sd = *(const float4*)(sdst + (long)myidx * NH);
    }
    const float4 ss = *(const float4*)(ssrc + (long)n * NH);

    float e0, e1, e2, e3;
    {
        float c0 = ss.x + sd.x, c1 = ss.y + sd.y, c2 = ss.z + sd.z, c3 = ss.w + sd.w;
        c0 = fmaxf(c0, 0.f) + 0.2f * fminf(c0, 0.f);
        c1 = fmaxf(c1, 0.f) + 0.2f * fminf(c1, 0.f);
        c2 = fmaxf(c2, 0.f) + 0.2f * fminf(c2, 0.f);
        c3 = fmaxf(c3, 0.f) + 0.2f * fminf(c3, 0.f);
        e0 = expf(c0); e1 = expf(c1); e2 = expf(c2); e3 = expf(c3);
    }
    if (lane >= 17) { e0 = e1 = e2 = e3 = -INFINITY; }

    // --- softmax over d (64-lane butterfly; lanes>=17 are -inf / 0) ---
    float m0 = e0, m1 = e1, m2 = e2, m3 = e3;
#pragma unroll
    for (int mask = 32; mask >= 1; mask >>= 1) {
        m0 = fmaxf(m0, __shfl_xor(m0, mask));
        m1 = fmaxf(m1, __shfl_xor(m1, mask));
        m2 = fmaxf(m2, __shfl_xor(m2, mask));
        m3 = fmaxf(m3, __shfl_xor(m3, mask));
    }
    float p0 = (lane < 17) ? expf(e0 - m0) : 0.f;
    float p1 = (lane < 17) ? expf(e1 - m1) : 0.f;
    float p2 = (lane < 17) ? expf(e2 - m2) : 0.f;
    float p3 = (lane < 17) ? expf(e3 - m3) : 0.f;
    float s0 = p0, s1 = p1, s2 = p2, s3 = p3;
#pragma unroll
    for (int mask = 32; mask >= 1; mask >>= 1) {
        s0 += __shfl_xor(s0, mask);
        s1 += __shfl_xor(s1, mask);
        s2 += __shfl_xor(s2, mask);
        s3 += __shfl_xor(s3, mask);
    }
    if (lane < 17) {
        salpha[wv][lane][0] = p0 / s0;
        salpha[wv][lane][1] = p1 / s1;
        salpha[wv][lane][2] = p2 / s2;
        salpha[wv][lane][3] = p3 / s3;
        sidx[wv][lane] = myidx;
    }
    __syncthreads();

    // --- phase 2: weighted feature gather ---
    const int hl = lane >> 5;  // head select: acc_lo -> head hl, acc_hi -> 2+hl
    float accL = 0.f, accH = 0.f;
#pragma unroll
    for (int d = 0; d < 17; ++d) {
        const int nb = sidx[wv][d];
        const float aL = salpha[wv][d][hl];
        const float aH = salpha[wv][d][2 + hl];
        const float* row = t + (long)nb * FTOT;
        accL += aL * row[lane];
        accH += aH * row[lane + 64];
    }

    // --- ELU + store ---
    const float yL = accL > 0.f ? accL : expm1f(accL);
    const float yH = accH > 0.f ? accH : expm1f(accH);
    out[(long)n * FTOT + lane] = yL;
    out[(long)n * FTOT + 64 + lane] = yH;
}

extern "C" void kernel_launch(void* const* d_in, const int* in_sizes, int n_in,
                              void* d_out, int out_size, void* d_ws, size_t ws_size,
                              hipStream_t stream) {
    const float* x = (const float*)d_in[0];
    const int* nidx = (const int*)d_in[1];
    const float* W = (const float*)d_in[2];   // Ws flattened: [h*32+o][i]
    const float* As = (const float*)d_in[3];  // [h][64]
    float* out = (float*)d_out;

    float* t = (float*)d_ws;                        // [NN][128]  51.2 MB
    float* ssrc = t + (size_t)NN * FTOT;            // [NN][4]     1.6 MB
    float* sdst = ssrc + (size_t)NN * NH;           // [NN][4]     1.6 MB

    dim3 g1((NN + 63) / 64, 2);
    k1_proj<<<g1, 256, 0, stream>>>(x, W, As, t, ssrc, sdst);

    k2_attn<<<(NN + 3) / 4, 256, 0, stream>>>(nidx, t, ssrc, sdst, out);
}

// Round 7
// 220.155 us; speedup vs baseline: 1.2945x; 1.2945x over previous
//
#include <hip/hip_runtime.h>
#include <hip/hip_fp16.h>
#include <math.h>

#define NN 100000
#define DEG 16
#define F_IN 128
#define F_OUT 32
#define NH 4
#define FTOT 128  // NH * F_OUT

#define BM 128    // nodes per block (k1)
#define BK 32     // k-chunk (k1)
#define PAD 132   // LDS row pad (floats): keeps ds_read_b128 2-way (free)

// ---------------------------------------------------------------------------
// Kernel 1: t[n][f] = sum_i x[n][i] * W[f][i]  (fp32 math, fp16 store)
//           ssrc/sdst[n][h] from the fp32 accumulators.
// 128 nodes x 128 feats per block, 8x8 register tile per lane (0.5 B/FLOP LDS),
// K chunked by 32, double-buffered LDS, reg-staged async prefetch.
// ---------------------------------------------------------------------------
__global__ __launch_bounds__(256) void k1_proj(
    const float* __restrict__ x,    // [NN][128]
    const float* __restrict__ W,    // [128][128] (h*32+o major)
    const float* __restrict__ As,   // [4][64]
    __half* __restrict__ t,         // [NN][128] fp16
    float* __restrict__ ssrc,       // [NN][4]
    float* __restrict__ sdst) {     // [NN][4]
    __shared__ float xs[2][BK][PAD];   // xs[buf][kk][node]
    __shared__ float ws_[2][BK][PAD];  // ws[buf][kk][feat]

    const int tid = threadIdx.x;
    const int base = blockIdx.x * BM;

    float4 rx[4], rw[4];  // staged chunk (32 floats each): regs -> LDS

    auto load_chunk = [&](int k0) {
#pragma unroll
        for (int r = 0; r < 4; ++r) {
            const int q = tid + 256 * r;
            const int n = q >> 3;    // row within tile (node / feat)
            const int c = q & 7;     // float4 index within 32-k chunk
            int ng = base + n;
            if (ng >= NN) ng = NN - 1;  // clamp; stores guarded later
            rx[r] = *(const float4*)(x + (long)ng * F_IN + k0 + 4 * c);
            rw[r] = *(const float4*)(W + n * F_IN + k0 + 4 * c);
        }
    };
    auto write_chunk = [&](int buf) {
#pragma unroll
        for (int r = 0; r < 4; ++r) {
            const int q = tid + 256 * r;
            const int n = q >> 3;
            const int c = q & 7;
            xs[buf][4 * c + 0][n] = rx[r].x;
            xs[buf][4 * c + 1][n] = rx[r].y;
            xs[buf][4 * c + 2][n] = rx[r].z;
            xs[buf][4 * c + 3][n] = rx[r].w;
            ws_[buf][4 * c + 0][n] = rw[r].x;
            ws_[buf][4 * c + 1][n] = rw[r].y;
            ws_[buf][4 * c + 2][n] = rw[r].z;
            ws_[buf][4 * c + 3][n] = rw[r].w;
        }
    };

    load_chunk(0);
    write_chunk(0);
    __syncthreads();
    load_chunk(32);  // chunk 1 in flight

    const int lane = tid & 63;
    const int wv = tid >> 6;
    const int wr = wv >> 1;            // node quadrant
    const int wc = wv & 1;             // feat quadrant
    const int ln = lane & 7;
    const int lf = lane >> 3;
    const int nq0 = wr * 64 + ln * 8;  // 8 nodes per lane
    const int fq0 = wc * 64 + lf * 8;  // 8 feats per lane

    float acc[8][8];
#pragma unroll
    for (int j = 0; j < 8; ++j)
#pragma unroll
        for (int q = 0; q < 8; ++q) acc[j][q] = 0.f;

    for (int ch = 0; ch < 4; ++ch) {
        const int buf = ch & 1;
#pragma unroll 8
        for (int kk = 0; kk < BK; ++kk) {
            const float4 xa = *(const float4*)&xs[buf][kk][nq0];
            const float4 xb = *(const float4*)&xs[buf][kk][nq0 + 4];
            const float4 wa = *(const float4*)&ws_[buf][kk][fq0];
            const float4 wb = *(const float4*)&ws_[buf][kk][fq0 + 4];
            const float xn[8] = {xa.x, xa.y, xa.z, xa.w, xb.x, xb.y, xb.z, xb.w};
            const float wf[8] = {wa.x, wa.y, wa.z, wa.w, wb.x, wb.y, wb.z, wb.w};
#pragma unroll
            for (int j = 0; j < 8; ++j)
#pragma unroll
                for (int q = 0; q < 8; ++q) acc[j][q] += xn[j] * wf[q];
        }
        if (ch < 3) {
            __syncthreads();          // everyone done reading buf^1
            write_chunk(buf ^ 1);     // chunk ch+1 regs -> LDS
            __syncthreads();
            if (ch < 2) load_chunk(32 * (ch + 2));  // prefetch chunk ch+2
        }
    }

    // --- t store (fp16, 16B per node-row-slice) ---
#pragma unroll
    for (int j = 0; j < 8; ++j) {
        const int n = base + nq0 + j;
        if (n < NN) {
            union { __half h[8]; float4 v; } u;
#pragma unroll
            for (int q = 0; q < 8; ++q) u.h[q] = __float2half_rn(acc[j][q]);
            *(float4*)(t + (long)n * FTOT + fq0) = u.v;
        }
    }

    // --- ssrc/sdst from fp32 acc: head h owns feats [h*32, h*32+32) ---
    const int h = wc * 2 + (lf >> 2);
    const int o0 = (lf & 3) * 8;
    const float4 a0 = *(const float4*)(As + h * 64 + o0);
    const float4 a1 = *(const float4*)(As + h * 64 + o0 + 4);
    const float4 b0 = *(const float4*)(As + h * 64 + 32 + o0);
    const float4 b1 = *(const float4*)(As + h * 64 + 32 + o0 + 4);
    const float av[8] = {a0.x, a0.y, a0.z, a0.w, a1.x, a1.y, a1.z, a1.w};
    const float bv[8] = {b0.x, b0.y, b0.z, b0.w, b1.x, b1.y, b1.z, b1.w};
#pragma unroll
    for (int j = 0; j < 8; ++j) {
        float ps = 0.f, pd = 0.f;
#pragma unroll
        for (int q = 0; q < 8; ++q) {
            ps += acc[j][q] * av[q];
            pd += acc[j][q] * bv[q];
        }
        ps += __shfl_xor(ps, 8);  ps += __shfl_xor(ps, 16);
        pd += __shfl_xor(pd, 8);  pd += __shfl_xor(pd, 16);
        if ((lf & 3) == 0) {
            const int n = base + nq0 + j;
            if (n < NN) {
                ssrc[(long)n * NH + h] = ps;
                sdst[(long)n * NH + h] = pd;
            }
        }
    }
}

// ---------------------------------------------------------------------------
// Kernel 2: one wave per node. fp16 t gather (256B/row, one coalesced
// instruction per edge), gathers prefetched into regs before the softmax
// phase so HBM/L3 latency hides under the score computation.
// ---------------------------------------------------------------------------
__global__ __launch_bounds__(256) void k2_attn(
    const int* __restrict__ nidx,    // [NN][16]
    const __half* __restrict__ t,    // [NN][128] fp16
    const float* __restrict__ ssrc,  // [NN][4]
    const float* __restrict__ sdst,  // [NN][4]
    float* __restrict__ out) {       // [NN][128]
    __shared__ float salpha[4][17][4];
    __shared__ int sidx[4][17];

    const int lane = threadIdx.x & 63;
    const int wv = threadIdx.x >> 6;
    const int n = blockIdx.x * 4 + wv;  // 25000 blocks x 4 waves = 100000 exact

    // --- phase A: indices + sdst loads (lanes 0..16) ---
    int myidx = 0;
    float4 sd = make_float4(0.f, 0.f, 0.f, 0.f);
    if (lane < 17) {
        myidx = (lane == 0) ? n : nidx[(long)n * DEG + (lane - 1)];
        sidx[wv][lane] = myidx;
        sd = *(const float4*)(sdst + (long)myidx * NH);
    }
    __syncthreads();

    // --- phase B: prefetch all 17 feature gathers (all 64 lanes, 4B each:
    //     wave covers the full 256B fp16 row per edge) ---
    unsigned int pre[17];
#pragma unroll
    for (int d = 0; d < 17; ++d) {
        const int nb = sidx[wv][d];
        pre[d] = *(const unsigned int*)(t + (long)nb * FTOT + 2 * lane);
    }

    // --- scores (overlaps with prefetch latency) ---
    const float4 ss = *(const float4*)(ssrc + (long)n * NH);
    float e0, e1, e2, e3;
    {
        float c0 = ss.x + sd.x, c1 = ss.y + sd.y, c2 = ss.z + sd.z, c3 = ss.w + sd.w;
        c0 = fmaxf(c0, 0.f) + 0.2f * fminf(c0, 0.f);
        c1 = fmaxf(c1, 0.f) + 0.2f * fminf(c1, 0.f);
        c2 = fmaxf(c2, 0.f) + 0.2f * fminf(c2, 0.f);
        c3 = fmaxf(c3, 0.f) + 0.2f * fminf(c3, 0.f);
        e0 = expf(c0); e1 = expf(c1); e2 = expf(c2); e3 = expf(c3);
    }
    if (lane >= 17) { e0 = e1 = e2 = e3 = -INFINITY; }

    // --- softmax over d: 5-round butterfly within 32-lane group ---
    float m0 = e0, m1 = e1, m2 = e2, m3 = e3;
#pragma unroll
    for (int mask = 16; mask >= 1; mask >>= 1) {
        m0 = fmaxf(m0, __shfl_xor(m0, mask));
        m1 = fmaxf(m1, __shfl_xor(m1, mask));
        m2 = fmaxf(m2, __shfl_xor(m2, mask));
        m3 = fmaxf(m3, __shfl_xor(m3, mask));
    }
    float p0 = (lane < 17) ? expf(e0 - m0) : 0.f;
    float p1 = (lane < 17) ? expf(e1 - m1) : 0.f;
    float p2 = (lane < 17) ? expf(e2 - m2) : 0.f;
    float p3 = (lane < 17) ? expf(e3 - m3) : 0.f;
    float s0 = p0, s1 = p1, s2 = p2, s3 = p3;
#pragma unroll
    for (int mask = 16; mask >= 1; mask >>= 1) {
        s0 += __shfl_xor(s0, mask);
        s1 += __shfl_xor(s1, mask);
        s2 += __shfl_xor(s2, mask);
        s3 += __shfl_xor(s3, mask);
    }
    if (lane < 17) {
        salpha[wv][lane][0] = p0 / s0;
        salpha[wv][lane][1] = p1 / s1;
        salpha[wv][lane][2] = p2 / s2;
        salpha[wv][lane][3] = p3 / s3;
    }
    __syncthreads();

    // --- phase C: weighted sum over prefetched rows ---
    const int h = lane >> 4;  // lane owns feats {2*lane, 2*lane+1}; head = f>>5
    float ax = 0.f, ay = 0.f;
#pragma unroll
    for (int d = 0; d < 17; ++d) {
        const float a = salpha[wv][d][h];
        const float2 f = __half22float2(*(const __half2*)&pre[d]);
        ax += a * f.x;
        ay += a * f.y;
    }

    // --- ELU + store (wave writes 512B contiguous) ---
    const float yx = ax > 0.f ? ax : expm1f(ax);
    const float yy = ay > 0.f ? ay : expm1f(ay);
    float2 o = make_float2(yx, yy);
    *(float2*)(out + (long)n * FTOT + 2 * lane) = o;
}

extern "C" void kernel_launch(void* const* d_in, const int* in_sizes, int n_in,
                              void* d_out, int out_size, void* d_ws, size_t ws_size,
                              hipStream_t stream) {
    const float* x = (const float*)d_in[0];
    const int* nidx = (const int*)d_in[1];
    const float* W = (const float*)d_in[2];   // Ws flattened: [h*32+o][i]
    const float* As = (const float*)d_in[3];  // [h][64]
    float* out = (float*)d_out;

    __half* t = (__half*)d_ws;                              // [NN][128] fp16, 25.6 MB
    float* ssrc = (float*)((char*)d_ws + (size_t)NN * FTOT * sizeof(__half));
    float* sdst = ssrc + (size_t)NN * NH;

    k1_proj<<<(NN + BM - 1) / BM, 256, 0, stream>>>(x, W, As, t, ssrc, sdst);
    k2_attn<<<NN / 4, 256, 0, stream>>>(nidx, t, ssrc, sdst, out);
}

// Round 8
// 219.515 us; speedup vs baseline: 1.2982x; 1.0029x over previous
//
#include <hip/hip_runtime.h>
#include <hip/hip_fp16.h>
#include <math.h>

#define NN 100000
#define DEG 16
#define F_IN 128
#define F_OUT 32
#define NH 4
#define FTOT 128  // NH * F_OUT

#define BM 128    // nodes per block (k1)
#define BK 32     // k-chunk (k1)
#define PAD 132   // LDS row pad (floats): keeps ds_read_b128 2-way (free)

// ---------------------------------------------------------------------------
// Kernel 1: t[n][f] = sum_i x[n][i] * W[f][i]  (fp32 math, fp16 store)
//           ssrc/sdst[n][h] from the fp32 accumulators.
// UNCHANGED from round 7 (measured <80 µs; exact dur still unattributed).
// ---------------------------------------------------------------------------
__global__ __launch_bounds__(256) void k1_proj(
    const float* __restrict__ x,    // [NN][128]
    const float* __restrict__ W,    // [128][128] (h*32+o major)
    const float* __restrict__ As,   // [4][64]
    __half* __restrict__ t,         // [NN][128] fp16
    float* __restrict__ ssrc,       // [NN][4]
    float* __restrict__ sdst) {     // [NN][4]
    __shared__ float xs[2][BK][PAD];   // xs[buf][kk][node]
    __shared__ float ws_[2][BK][PAD];  // ws[buf][kk][feat]

    const int tid = threadIdx.x;
    const int base = blockIdx.x * BM;

    float4 rx[4], rw[4];  // staged chunk (32 floats each): regs -> LDS

    auto load_chunk = [&](int k0) {
#pragma unroll
        for (int r = 0; r < 4; ++r) {
            const int q = tid + 256 * r;
            const int n = q >> 3;    // row within tile (node / feat)
            const int c = q & 7;     // float4 index within 32-k chunk
            int ng = base + n;
            if (ng >= NN) ng = NN - 1;  // clamp; stores guarded later
            rx[r] = *(const float4*)(x + (long)ng * F_IN + k0 + 4 * c);
            rw[r] = *(const float4*)(W + n * F_IN + k0 + 4 * c);
        }
    };
    auto write_chunk = [&](int buf) {
#pragma unroll
        for (int r = 0; r < 4; ++r) {
            const int q = tid + 256 * r;
            const int n = q >> 3;
            const int c = q & 7;
            xs[buf][4 * c + 0][n] = rx[r].x;
            xs[buf][4 * c + 1][n] = rx[r].y;
            xs[buf][4 * c + 2][n] = rx[r].z;
            xs[buf][4 * c + 3][n] = rx[r].w;
            ws_[buf][4 * c + 0][n] = rw[r].x;
            ws_[buf][4 * c + 1][n] = rw[r].y;
            ws_[buf][4 * c + 2][n] = rw[r].z;
            ws_[buf][4 * c + 3][n] = rw[r].w;
        }
    };

    load_chunk(0);
    write_chunk(0);
    __syncthreads();
    load_chunk(32);  // chunk 1 in flight

    const int lane = tid & 63;
    const int wv = tid >> 6;
    const int wr = wv >> 1;            // node quadrant
    const int wc = wv & 1;             // feat quadrant
    const int ln = lane & 7;
    const int lf = lane >> 3;
    const int nq0 = wr * 64 + ln * 8;  // 8 nodes per lane
    const int fq0 = wc * 64 + lf * 8;  // 8 feats per lane

    float acc[8][8];
#pragma unroll
    for (int j = 0; j < 8; ++j)
#pragma unroll
        for (int q = 0; q < 8; ++q) acc[j][q] = 0.f;

    for (int ch = 0; ch < 4; ++ch) {
        const int buf = ch & 1;
#pragma unroll 8
        for (int kk = 0; kk < BK; ++kk) {
            const float4 xa = *(const float4*)&xs[buf][kk][nq0];
            const float4 xb = *(const float4*)&xs[buf][kk][nq0 + 4];
            const float4 wa = *(const float4*)&ws_[buf][kk][fq0];
            const float4 wb = *(const float4*)&ws_[buf][kk][fq0 + 4];
            const float xn[8] = {xa.x, xa.y, xa.z, xa.w, xb.x, xb.y, xb.z, xb.w};
            const float wf[8] = {wa.x, wa.y, wa.z, wa.w, wb.x, wb.y, wb.z, wb.w};
#pragma unroll
            for (int j = 0; j < 8; ++j)
#pragma unroll
                for (int q = 0; q < 8; ++q) acc[j][q] += xn[j] * wf[q];
        }
        if (ch < 3) {
            __syncthreads();          // everyone done reading buf^1
            write_chunk(buf ^ 1);     // chunk ch+1 regs -> LDS
            __syncthreads();
            if (ch < 2) load_chunk(32 * (ch + 2));  // prefetch chunk ch+2
        }
    }

    // --- t store (fp16, 16B per node-row-slice) ---
#pragma unroll
    for (int j = 0; j < 8; ++j) {
        const int n = base + nq0 + j;
        if (n < NN) {
            union { __half h[8]; float4 v; } u;
#pragma unroll
            for (int q = 0; q < 8; ++q) u.h[q] = __float2half_rn(acc[j][q]);
            *(float4*)(t + (long)n * FTOT + fq0) = u.v;
        }
    }

    // --- ssrc/sdst from fp32 acc: head h owns feats [h*32, h*32+32) ---
    const int h = wc * 2 + (lf >> 2);
    const int o0 = (lf & 3) * 8;
    const float4 a0 = *(const float4*)(As + h * 64 + o0);
    const float4 a1 = *(const float4*)(As + h * 64 + o0 + 4);
    const float4 b0 = *(const float4*)(As + h * 64 + 32 + o0);
    const float4 b1 = *(const float4*)(As + h * 64 + 32 + o0 + 4);
    const float av[8] = {a0.x, a0.y, a0.z, a0.w, a1.x, a1.y, a1.z, a1.w};
    const float bv[8] = {b0.x, b0.y, b0.z, b0.w, b1.x, b1.y, b1.z, b1.w};
#pragma unroll
    for (int j = 0; j < 8; ++j) {
        float ps = 0.f, pd = 0.f;
#pragma unroll
        for (int q = 0; q < 8; ++q) {
            ps += acc[j][q] * av[q];
            pd += acc[j][q] * bv[q];
        }
        ps += __shfl_xor(ps, 8);  ps += __shfl_xor(ps, 16);
        pd += __shfl_xor(pd, 8);  pd += __shfl_xor(pd, 16);
        if ((lf & 3) == 0) {
            const int n = base + nq0 + j;
            if (n < NN) {
                ssrc[(long)n * NH + h] = ps;
                sdst[(long)n * NH + h] = pd;
            }
        }
    }
}

// ---------------------------------------------------------------------------
// Kernel 2 (RESTRUCTURED): one wave per node.
// Score phase now uses all 64 lanes: lane = h*16 + j handles (head h, edge j);
// lane j==15 also takes edge 16. All 4 heads reduce concurrently within their
// 16-lane group (4 shfl rounds/phase, 8 total vs 40 before). Feature-gather
// prefetch issues before the score phase so L2/L3 latency hides under it.
// ---------------------------------------------------------------------------
__global__ __launch_bounds__(256) void k2_attn(
    const int* __restrict__ nidx,    // [NN][16]
    const __half* __restrict__ t,    // [NN][128] fp16
    const float* __restrict__ ssrc,  // [NN][4]
    const float* __restrict__ sdst,  // [NN][4]
    float* __restrict__ out) {       // [NN][128]
    __shared__ float salpha[4][17][4];  // [wave][edge][head]
    __shared__ int sidx[4][17];

    const int lane = threadIdx.x & 63;
    const int wv = threadIdx.x >> 6;
    const int n = blockIdx.x * 4 + wv;  // 25000 blocks x 4 waves = 100000 exact

    // --- phase A: stage edge indices (lanes 0..16) ---
    if (lane < 17) {
        sidx[wv][lane] = (lane == 0) ? n : nidx[(long)n * DEG + (lane - 1)];
    }
    __syncthreads();

    // --- phase B: prefetch all 17 feature rows (4B/lane; wave covers the
    //     full 256B fp16 row per edge in one coalesced load) ---
    unsigned int pre[17];
#pragma unroll
    for (int d = 0; d < 17; ++d) {
        pre[d] = *(const unsigned int*)(t + (long)sidx[wv][d] * FTOT + 2 * lane);
    }

    // --- score phase: lane = h*16 + j -> e[h][j]; j==15 also does edge 16 ---
    const int h = lane >> 4;
    const int j = lane & 15;
    const float ssv = ssrc[(long)n * NH + h];

    float e_a;
    {
        float c = ssv + sdst[(long)sidx[wv][j] * NH + h];
        c = fmaxf(c, 0.f) + 0.2f * fminf(c, 0.f);
        e_a = expf(c);
    }
    float e_b = -INFINITY;
    if (j == 15) {
        float c = ssv + sdst[(long)sidx[wv][16] * NH + h];
        c = fmaxf(c, 0.f) + 0.2f * fminf(c, 0.f);
        e_b = expf(c);
    }

    // --- softmax over the 17 e-values, concurrently for all 4 heads:
    //     butterfly stays inside each 16-lane group (masks 8..1) ---
    float m = fmaxf(e_a, e_b);
#pragma unroll
    for (int mask = 8; mask >= 1; mask >>= 1)
        m = fmaxf(m, __shfl_xor(m, mask));

    const float pa = expf(e_a - m);
    const float pb = (j == 15) ? expf(e_b - m) : 0.f;
    float s = pa + pb;
#pragma unroll
    for (int mask = 8; mask >= 1; mask >>= 1)
        s += __shfl_xor(s, mask);

    const float inv = 1.0f / s;
    salpha[wv][j][h] = pa * inv;
    if (j == 15) salpha[wv][16][h] = pb * inv;
    __syncthreads();

    // --- phase C: weighted sum over prefetched rows ---
    const int hc = lane >> 4;  // lane owns feats {2*lane, 2*lane+1}; head = f>>5
    float ax = 0.f, ay = 0.f;
#pragma unroll
    for (int d = 0; d < 17; ++d) {
        const float a = salpha[wv][d][hc];
        const float2 f = __half22float2(*(const __half2*)&pre[d]);
        ax += a * f.x;
        ay += a * f.y;
    }

    // --- ELU + store (wave writes 512B contiguous) ---
    const float yx = ax > 0.f ? ax : expm1f(ax);
    const float yy = ay > 0.f ? ay : expm1f(ay);
    float2 o = make_float2(yx, yy);
    *(float2*)(out + (long)n * FTOT + 2 * lane) = o;
}

extern "C" void kernel_launch(void* const* d_in, const int* in_sizes, int n_in,
                              void* d_out, int out_size, void* d_ws, size_t ws_size,
                              hipStream_t stream) {
    const float* x = (const float*)d_in[0];
    const int* nidx = (const int*)d_in[1];
    const float* W = (const float*)d_in[2];   // Ws flattened: [h*32+o][i]
    const float* As = (const float*)d_in[3];  // [h][64]
    float* out = (float*)d_out;

    __half* t = (__half*)d_ws;                              // [NN][128] fp16, 25.6 MB
    float* ssrc = (float*)((char*)d_ws + (size_t)NN * FTOT * sizeof(__half));
    float* sdst = ssrc + (size_t)NN * NH;

    k1_proj<<<(NN + BM - 1) / BM, 256, 0, stream>>>(x, W, As, t, ssrc, sdst);
    k2_attn<<<NN / 4, 256, 0, stream>>>(nidx, t, ssrc, sdst, out);
}

// Round 10
// 192.134 us; speedup vs baseline: 1.4832x; 1.1425x over previous
//
#include <hip/hip_runtime.h>
#include <hip/hip_fp16.h>
#include <math.h>

#define NN 100000
#define DEG 16
#define F_IN 128
#define F_OUT 32
#define NH 4
#define FTOT 128  // NH * F_OUT

typedef _Float16 f16x8 __attribute__((ext_vector_type(8)));
typedef float f32x4 __attribute__((ext_vector_type(4)));

// Swizzled half-index into a row-major [R][128] __half LDS tile.
// XOR bits 3-5 (16B granules) with row&7: breaks the 256B-row bank alignment
// (G4: row-major at D=128 is otherwise a heavy conflict on 16B frag reads).
__device__ __forceinline__ int swz(int row, int col) {
    return row * 128 + (col ^ ((row & 7) << 3));
}

// ---------------------------------------------------------------------------
// Kernel 1 (MFMA): t[n][f] = sum_i x[n][i] * W[f][i], f16 inputs, f32 accum.
// Block = 64 nodes, 4 waves; wave owns 16 nodes (one MFMA m-tile) x 128 feats
// (8 n-tiles) x K=128 (4 k-steps). A/B frags use the SAME k-mapping, so any
// k-permutation assumption cancels; C/D uses the m89-verified mapping:
// col = lane&15, row = (lane>>4)*4 + reg.
// ssrc/sdst computed from the f32 accumulators (shfl-reduce over lane&15).
// ---------------------------------------------------------------------------
__global__ __launch_bounds__(256) void k1_proj(
    const float* __restrict__ x,    // [NN][128]
    const float* __restrict__ W,    // [128][128] (h*32+o major)
    const float* __restrict__ As,   // [4][64]
    __half* __restrict__ t,         // [NN][128] fp16
    float* __restrict__ ssrc,       // [NN][4]
    float* __restrict__ sdst) {     // [NN][4]
    __shared__ __half xs[64 * 128];    // 16 KB, swizzled; reused for t-stage
    __shared__ __half wsh[128 * 128];  // 32 KB, swizzled

    const int tid = threadIdx.x;
    const int base = blockIdx.x * 64;

    // --- stage x (fp32 -> fp16, swizzled): row = tid>>2, 32 floats each ---
    {
        const int row = tid >> 2;
        const int q = tid & 3;
        int ng = base + row;
        if (ng >= NN) ng = NN - 1;  // clamp loads; stores guarded later
        const float* src = x + (long)ng * F_IN + q * 32;
#pragma unroll
        for (int i = 0; i < 4; ++i) {
            const float4 v0 = *(const float4*)(src + i * 8);
            const float4 v1 = *(const float4*)(src + i * 8 + 4);
            union { __half2 h2[4]; float4 f; } u;
            u.h2[0] = __float22half2_rn(make_float2(v0.x, v0.y));
            u.h2[1] = __float22half2_rn(make_float2(v0.z, v0.w));
            u.h2[2] = __float22half2_rn(make_float2(v1.x, v1.y));
            u.h2[3] = __float22half2_rn(make_float2(v1.z, v1.w));
            *(float4*)&xs[swz(row, q * 32 + i * 8)] = u.f;
        }
    }
    // --- stage W (fp32 -> fp16, swizzled): row = tid>>1, 64 floats each ---
    {
        const int row = tid >> 1;
        const int hq = tid & 1;
        const float* src = W + row * F_IN + hq * 64;
#pragma unroll
        for (int i = 0; i < 8; ++i) {
            const float4 v0 = *(const float4*)(src + i * 8);
            const float4 v1 = *(const float4*)(src + i * 8 + 4);
            union { __half2 h2[4]; float4 f; } u;
            u.h2[0] = __float22half2_rn(make_float2(v0.x, v0.y));
            u.h2[1] = __float22half2_rn(make_float2(v0.z, v0.w));
            u.h2[2] = __float22half2_rn(make_float2(v1.x, v1.y));
            u.h2[3] = __float22half2_rn(make_float2(v1.z, v1.w));
            *(float4*)&wsh[swz(row, hq * 64 + i * 8)] = u.f;
        }
    }
    __syncthreads();

    const int lane = tid & 63;
    const int wv = tid >> 6;
    const int mb = wv * 16;    // wave's local node base
    const int lr = lane & 15;  // A-row (node) / B-col (feat) within tile
    const int lg = lane >> 4;  // k-group

    // A fragments: a[kk][j] = x[mb+lr][kk*32 + lg*8 + j]  (16B contiguous)
    f16x8 afr[4];
#pragma unroll
    for (int kk = 0; kk < 4; ++kk)
        afr[kk] = *(const f16x8*)&xs[swz(mb + lr, kk * 32 + lg * 8)];

    // 8 n-tiles of 16 feats; B frag uses the SAME k-mapping as A.
    f32x4 acc[8];
#pragma unroll
    for (int nt = 0; nt < 8; ++nt) {
        f32x4 c = {0.f, 0.f, 0.f, 0.f};
#pragma unroll
        for (int kk = 0; kk < 4; ++kk) {
            const f16x8 b =
                *(const f16x8*)&wsh[swz(nt * 16 + lr, kk * 32 + lg * 8)];
            c = __builtin_amdgcn_mfma_f32_16x16x32_f16(afr[kk], b, c, 0, 0, 0);
        }
        acc[nt] = c;
    }

    // --- t store: stage fp16 into the wave's own xs region (its A rows are
    //     fully consumed into afr, no cross-wave readers), then coalesced
    //     float4 global stores. Per-element swizzle = 16B-block permute. ---
    __half* tst = &xs[mb * 128];
#pragma unroll
    for (int nt = 0; nt < 8; ++nt) {
#pragma unroll
        for (int r = 0; r < 4; ++r) {
            const int node = lg * 4 + r;           // C/D row (verified m89)
            const int feat = nt * 16 + lr;         // C/D col
            tst[node * 128 + (feat ^ ((node & 7) << 3))] =
                __float2half_rn(acc[nt][r]);
        }
    }
#pragma unroll
    for (int r = 0; r < 4; ++r) {
        const int row = r * 4 + lg;
        const int n = base + mb + row;
        if (n < NN) {
            const float4 v =
                *(const float4*)&tst[row * 128 + ((lr * 8) ^ ((row & 7) << 3))];
            *(float4*)(t + (long)n * FTOT + lr * 8) = v;
        }
    }

    // --- ssrc/sdst from f32 acc: head h = feats [h*32, h*32+32) = n-tiles
    //     {2h, 2h+1}; reduce over lr (16-lane groups) ---
#pragma unroll
    for (int h = 0; h < NH; ++h) {
        const float as0 = As[h * 64 + lr];
        const float as1 = As[h * 64 + 16 + lr];
        const float ad0 = As[h * 64 + 32 + lr];
        const float ad1 = As[h * 64 + 48 + lr];
#pragma unroll
        for (int r = 0; r < 4; ++r) {
            float ps = acc[2 * h][r] * as0 + acc[2 * h + 1][r] * as1;
            float pd = acc[2 * h][r] * ad0 + acc[2 * h + 1][r] * ad1;
            ps += __shfl_xor(ps, 1); ps += __shfl_xor(ps, 2);
            ps += __shfl_xor(ps, 4); ps += __shfl_xor(ps, 8);
            pd += __shfl_xor(pd, 1); pd += __shfl_xor(pd, 2);
            pd += __shfl_xor(pd, 4); pd += __shfl_xor(pd, 8);
            if (lr == 0) {
                const int n = base + mb + lg * 4 + r;
                if (n < NN) {
                    ssrc[(long)n * NH + h] = ps;
                    sdst[(long)n * NH + h] = pd;
                }
            }
        }
    }
}

// ---------------------------------------------------------------------------
// Kernel 2: one wave per node (structure from round 8). New: nontemporal
// out-store and nidx-load so the 51+6 MB streams stop evicting the 25.6 MB
// t table from the per-XCD L2s (k2 is fetch-path-bound, not VALU-bound).
// ---------------------------------------------------------------------------
__global__ __launch_bounds__(256) void k2_attn(
    const int* __restrict__ nidx,    // [NN][16]
    const __half* __restrict__ t,    // [NN][128] fp16
    const float* __restrict__ ssrc,  // [NN][4]
    const float* __restrict__ sdst,  // [NN][4]
    float* __restrict__ out) {       // [NN][128]
    __shared__ float salpha[4][17][4];  // [wave][edge][head]
    __shared__ int sidx[4][17];

    const int lane = threadIdx.x & 63;
    const int wv = threadIdx.x >> 6;
    const int n = blockIdx.x * 4 + wv;  // 25000 blocks x 4 waves = 100000

    // --- phase A: stage edge indices (lanes 0..16) ---
    if (lane < 17) {
        sidx[wv][lane] =
            (lane == 0)
                ? n
                : __builtin_nontemporal_load(&nidx[(long)n * DEG + (lane - 1)]);
    }
    __syncthreads();

    // --- phase B: prefetch all 17 feature rows (4B/lane; wave covers the
    //     full 256B fp16 row per edge in one coalesced load) ---
    unsigned int pre[17];
#pragma unroll
    for (int d = 0; d < 17; ++d) {
        pre[d] = *(const unsigned int*)(t + (long)sidx[wv][d] * FTOT + 2 * lane);
    }

    // --- score phase: lane = h*16 + j -> e[h][j]; j==15 also does edge 16 ---
    const int h = lane >> 4;
    const int j = lane & 15;
    const float ssv = ssrc[(long)n * NH + h];

    float e_a;
    {
        float c = ssv + sdst[(long)sidx[wv][j] * NH + h];
        c = fmaxf(c, 0.f) + 0.2f * fminf(c, 0.f);
        e_a = expf(c);
    }
    float e_b = -INFINITY;
    if (j == 15) {
        float c = ssv + sdst[(long)sidx[wv][16] * NH + h];
        c = fmaxf(c, 0.f) + 0.2f * fminf(c, 0.f);
        e_b = expf(c);
    }

    // --- softmax over 17 e-values, all 4 heads concurrently (16-lane groups) ---
    float m = fmaxf(e_a, e_b);
#pragma unroll
    for (int mask = 8; mask >= 1; mask >>= 1)
        m = fmaxf(m, __shfl_xor(m, mask));

    const float pa = expf(e_a - m);
    const float pb = (j == 15) ? expf(e_b - m) : 0.f;
    float s = pa + pb;
#pragma unroll
    for (int mask = 8; mask >= 1; mask >>= 1)
        s += __shfl_xor(s, mask);

    const float inv = 1.0f / s;
    salpha[wv][j][h] = pa * inv;
    if (j == 15) salpha[wv][16][h] = pb * inv;
    __syncthreads();

    // --- phase C: weighted sum over prefetched rows ---
    const int hc = lane >> 4;  // lane owns feats {2*lane, 2*lane+1}
    float ax = 0.f, ay = 0.f;
#pragma unroll
    for (int d = 0; d < 17; ++d) {
        const float a = salpha[wv][d][hc];
        const float2 f = __half22float2(*(const __half2*)&pre[d]);
        ax += a * f.x;
        ay += a * f.y;
    }

    // --- ELU + nontemporal store (out is write-once: keep it out of L2) ---
    const float yx = ax > 0.f ? ax : expm1f(ax);
    const float yy = ay > 0.f ? ay : expm1f(ay);
    union { float2 f2; double d; } o;
    o.f2 = make_float2(yx, yy);
    __builtin_nontemporal_store(o.d, (double*)(out + (long)n * FTOT + 2 * lane));
}

extern "C" void kernel_launch(void* const* d_in, const int* in_sizes, int n_in,
                              void* d_out, int out_size, void* d_ws, size_t ws_size,
                              hipStream_t stream) {
    const float* x = (const float*)d_in[0];
    const int* nidx = (const int*)d_in[1];
    const float* W = (const float*)d_in[2];   // Ws flattened: [h*32+o][i]
    const float* As = (const float*)d_in[3];  // [h][64]
    float* out = (float*)d_out;

    __half* t = (__half*)d_ws;                              // [NN][128] fp16
    float* ssrc = (float*)((char*)d_ws + (size_t)NN * FTOT * sizeof(__half));
    float* sdst = ssrc + (size_t)NN * NH;

    k1_proj<<<(NN + 63) / 64, 256, 0, stream>>>(x, W, As, t, ssrc, sdst);
    k2_attn<<<NN / 4, 256, 0, stream>>>(nidx, t, ssrc, sdst, out);
}

// Round 11
// 188.006 us; speedup vs baseline: 1.5158x; 1.0220x over previous
//
#include <hip/hip_runtime.h>
#include <hip/hip_fp16.h>
#include <math.h>

#define NN 100000
#define DEG 16
#define F_IN 128
#define F_OUT 32
#define NH 4
#define FTOT 128  // NH * F_OUT

typedef _Float16 f16x8 __attribute__((ext_vector_type(8)));
typedef float f32x4 __attribute__((ext_vector_type(4)));

// Swizzled half-index into a row-major [R][128] __half tile.
// XOR bits 3-5 (16B granules) with row&7: breaks the 256B-row bank alignment
// (G4: row-major at D=128 is otherwise a heavy conflict on 16B frag reads).
__device__ __forceinline__ int swz(int row, int col) {
    return row * 128 + (col ^ ((row & 7) << 3));
}

// ---------------------------------------------------------------------------
// Kernel 0: one-time W fp32 -> fp16 convert, stored in the SAME swizzled
// layout k1's LDS uses, so k1 stages W with a plain linear 32 KB copy.
// 2048 threads, each handles one 8-half granule.
// ---------------------------------------------------------------------------
__global__ __launch_bounds__(256) void k0_wprep(
    const float* __restrict__ W,    // [128][128]
    __half* __restrict__ W16) {     // [128*128] swizzled
    const int g = blockIdx.x * 256 + threadIdx.x;  // 0..2047
    const int row = g >> 4;
    const int col = (g & 15) * 8;
    const float4 v0 = *(const float4*)(W + row * F_IN + col);
    const float4 v1 = *(const float4*)(W + row * F_IN + col + 4);
    union { __half2 h2[4]; float4 f; } u;
    u.h2[0] = __float22half2_rn(make_float2(v0.x, v0.y));
    u.h2[1] = __float22half2_rn(make_float2(v0.z, v0.w));
    u.h2[2] = __float22half2_rn(make_float2(v1.x, v1.y));
    u.h2[3] = __float22half2_rn(make_float2(v1.z, v1.w));
    *(float4*)&W16[swz(row, col)] = u.f;
}

// ---------------------------------------------------------------------------
// Kernel 1 (MFMA): t[n][f] = sum_i x[n][i] * W[f][i], f16 inputs, f32 accum.
// Identical to the round-8 verified kernel EXCEPT the W stage is now a
// linear copy of the pre-swizzled W16 (no per-block fp32 re-read / convert).
// ---------------------------------------------------------------------------
__global__ __launch_bounds__(256) void k1_proj(
    const float* __restrict__ x,     // [NN][128]
    const __half* __restrict__ W16,  // [128*128] swizzled fp16
    const float* __restrict__ As,    // [4][64]
    __half* __restrict__ t,          // [NN][128] fp16
    float* __restrict__ ssrc,        // [NN][4]
    float* __restrict__ sdst) {      // [NN][4]
    __shared__ __half xs[64 * 128];    // 16 KB, swizzled; reused for t-stage
    __shared__ __half wsh[128 * 128];  // 32 KB, swizzled

    const int tid = threadIdx.x;
    const int base = blockIdx.x * 64;

    // --- stage x (fp32 -> fp16, swizzled): row = tid>>2, 32 floats each ---
    {
        const int row = tid >> 2;
        const int q = tid & 3;
        int ng = base + row;
        if (ng >= NN) ng = NN - 1;  // clamp loads; stores guarded later
        const float* src = x + (long)ng * F_IN + q * 32;
#pragma unroll
        for (int i = 0; i < 4; ++i) {
            const float4 v0 = *(const float4*)(src + i * 8);
            const float4 v1 = *(const float4*)(src + i * 8 + 4);
            union { __half2 h2[4]; float4 f; } u;
            u.h2[0] = __float22half2_rn(make_float2(v0.x, v0.y));
            u.h2[1] = __float22half2_rn(make_float2(v0.z, v0.w));
            u.h2[2] = __float22half2_rn(make_float2(v1.x, v1.y));
            u.h2[3] = __float22half2_rn(make_float2(v1.z, v1.w));
            *(float4*)&xs[swz(row, q * 32 + i * 8)] = u.f;
        }
    }
    // --- stage W: linear 32 KB copy (swizzle pre-baked by k0_wprep) ---
    {
        const float4* src = (const float4*)W16;
        float4* dst = (float4*)wsh;
#pragma unroll
        for (int i = 0; i < 8; ++i) dst[tid + 256 * i] = src[tid + 256 * i];
    }
    __syncthreads();

    const int lane = tid & 63;
    const int wv = tid >> 6;
    const int mb = wv * 16;    // wave's local node base
    const int lr = lane & 15;  // A-row (node) / B-col (feat) within tile
    const int lg = lane >> 4;  // k-group

    // A fragments: a[kk][j] = x[mb+lr][kk*32 + lg*8 + j]  (16B contiguous)
    f16x8 afr[4];
#pragma unroll
    for (int kk = 0; kk < 4; ++kk)
        afr[kk] = *(const f16x8*)&xs[swz(mb + lr, kk * 32 + lg * 8)];

    // 8 n-tiles of 16 feats; B frag uses the SAME k-mapping as A.
    f32x4 acc[8];
#pragma unroll
    for (int nt = 0; nt < 8; ++nt) {
        f32x4 c = {0.f, 0.f, 0.f, 0.f};
#pragma unroll
        for (int kk = 0; kk < 4; ++kk) {
            const f16x8 b =
                *(const f16x8*)&wsh[swz(nt * 16 + lr, kk * 32 + lg * 8)];
            c = __builtin_amdgcn_mfma_f32_16x16x32_f16(afr[kk], b, c, 0, 0, 0);
        }
        acc[nt] = c;
    }

    // --- t store: stage fp16 into the wave's own xs region (its A rows are
    //     fully consumed into afr, no cross-wave readers), then coalesced
    //     float4 global stores. Per-element swizzle = 16B-block permute. ---
    __half* tst = &xs[mb * 128];
#pragma unroll
    for (int nt = 0; nt < 8; ++nt) {
#pragma unroll
        for (int r = 0; r < 4; ++r) {
            const int node = lg * 4 + r;           // C/D row (verified m89)
            const int feat = nt * 16 + lr;         // C/D col
            tst[node * 128 + (feat ^ ((node & 7) << 3))] =
                __float2half_rn(acc[nt][r]);
        }
    }
#pragma unroll
    for (int r = 0; r < 4; ++r) {
        const int row = r * 4 + lg;
        const int n = base + mb + row;
        if (n < NN) {
            const float4 v =
                *(const float4*)&tst[row * 128 + ((lr * 8) ^ ((row & 7) << 3))];
            *(float4*)(t + (long)n * FTOT + lr * 8) = v;
        }
    }

    // --- ssrc/sdst from f32 acc: head h = feats [h*32, h*32+32) = n-tiles
    //     {2h, 2h+1}; reduce over lr (16-lane groups) ---
#pragma unroll
    for (int h = 0; h < NH; ++h) {
        const float as0 = As[h * 64 + lr];
        const float as1 = As[h * 64 + 16 + lr];
        const float ad0 = As[h * 64 + 32 + lr];
        const float ad1 = As[h * 64 + 48 + lr];
#pragma unroll
        for (int r = 0; r < 4; ++r) {
            float ps = acc[2 * h][r] * as0 + acc[2 * h + 1][r] * as1;
            float pd = acc[2 * h][r] * ad0 + acc[2 * h + 1][r] * ad1;
            ps += __shfl_xor(ps, 1); ps += __shfl_xor(ps, 2);
            ps += __shfl_xor(ps, 4); ps += __shfl_xor(ps, 8);
            pd += __shfl_xor(pd, 1); pd += __shfl_xor(pd, 2);
            pd += __shfl_xor(pd, 4); pd += __shfl_xor(pd, 8);
            if (lr == 0) {
                const int n = base + mb + lg * 4 + r;
                if (n < NN) {
                    ssrc[(long)n * NH + h] = ps;
                    sdst[(long)n * NH + h] = pd;
                }
            }
        }
    }
}

// ---------------------------------------------------------------------------
// Kernel 2: FROZEN from round 10 (control for attribution).
// ---------------------------------------------------------------------------
__global__ __launch_bounds__(256) void k2_attn(
    const int* __restrict__ nidx,    // [NN][16]
    const __half* __restrict__ t,    // [NN][128] fp16
    const float* __restrict__ ssrc,  // [NN][4]
    const float* __restrict__ sdst,  // [NN][4]
    float* __restrict__ out) {       // [NN][128]
    __shared__ float salpha[4][17][4];  // [wave][edge][head]
    __shared__ int sidx[4][17];

    const int lane = threadIdx.x & 63;
    const int wv = threadIdx.x >> 6;
    const int n = blockIdx.x * 4 + wv;  // 25000 blocks x 4 waves = 100000

    // --- phase A: stage edge indices (lanes 0..16) ---
    if (lane < 17) {
        sidx[wv][lane] =
            (lane == 0)
                ? n
                : __builtin_nontemporal_load(&nidx[(long)n * DEG + (lane - 1)]);
    }
    __syncthreads();

    // --- phase B: prefetch all 17 feature rows (4B/lane; wave covers the
    //     full 256B fp16 row per edge in one coalesced load) ---
    unsigned int pre[17];
#pragma unroll
    for (int d = 0; d < 17; ++d) {
        pre[d] = *(const unsigned int*)(t + (long)sidx[wv][d] * FTOT + 2 * lane);
    }

    // --- score phase: lane = h*16 + j -> e[h][j]; j==15 also does edge 16 ---
    const int h = lane >> 4;
    const int j = lane & 15;
    const float ssv = ssrc[(long)n * NH + h];

    float e_a;
    {
        float c = ssv + sdst[(long)sidx[wv][j] * NH + h];
        c = fmaxf(c, 0.f) + 0.2f * fminf(c, 0.f);
        e_a = expf(c);
    }
    float e_b = -INFINITY;
    if (j == 15) {
        float c = ssv + sdst[(long)sidx[wv][16] * NH + h];
        c = fmaxf(c, 0.f) + 0.2f * fminf(c, 0.f);
        e_b = expf(c);
    }

    // --- softmax over 17 e-values, all 4 heads concurrently (16-lane groups) ---
    float m = fmaxf(e_a, e_b);
#pragma unroll
    for (int mask = 8; mask >= 1; mask >>= 1)
        m = fmaxf(m, __shfl_xor(m, mask));

    const float pa = expf(e_a - m);
    const float pb = (j == 15) ? expf(e_b - m) : 0.f;
    float s = pa + pb;
#pragma unroll
    for (int mask = 8; mask >= 1; mask >>= 1)
        s += __shfl_xor(s, mask);

    const float inv = 1.0f / s;
    salpha[wv][j][h] = pa * inv;
    if (j == 15) salpha[wv][16][h] = pb * inv;
    __syncthreads();

    // --- phase C: weighted sum over prefetched rows ---
    const int hc = lane >> 4;  // lane owns feats {2*lane, 2*lane+1}
    float ax = 0.f, ay = 0.f;
#pragma unroll
    for (int d = 0; d < 17; ++d) {
        const float a = salpha[wv][d][hc];
        const float2 f = __half22float2(*(const __half2*)&pre[d]);
        ax += a * f.x;
        ay += a * f.y;
    }

    // --- ELU + nontemporal store (out is write-once: keep it out of L2) ---
    const float yx = ax > 0.f ? ax : expm1f(ax);
    const float yy = ay > 0.f ? ay : expm1f(ay);
    union { float2 f2; double d; } o;
    o.f2 = make_float2(yx, yy);
    __builtin_nontemporal_store(o.d, (double*)(out + (long)n * FTOT + 2 * lane));
}

extern "C" void kernel_launch(void* const* d_in, const int* in_sizes, int n_in,
                              void* d_out, int out_size, void* d_ws, size_t ws_size,
                              hipStream_t stream) {
    const float* x = (const float*)d_in[0];
    const int* nidx = (const int*)d_in[1];
    const float* W = (const float*)d_in[2];   // Ws flattened: [h*32+o][i]
    const float* As = (const float*)d_in[3];  // [h][64]
    float* out = (float*)d_out;

    __half* t = (__half*)d_ws;                              // [NN][128] fp16
    float* ssrc = (float*)((char*)d_ws + (size_t)NN * FTOT * sizeof(__half));
    float* sdst = ssrc + (size_t)NN * NH;
    __half* W16 = (__half*)(sdst + (size_t)NN * NH);        // [128*128] swizzled

    k0_wprep<<<8, 256, 0, stream>>>(W, W16);
    k1_proj<<<(NN + 63) / 64, 256, 0, stream>>>(x, W16, As, t, ssrc, sdst);
    k2_attn<<<NN / 4, 256, 0, stream>>>(nidx, t, ssrc, sdst, out);
}